// Round 2
// baseline (533.021 us; speedup 1.0000x reference)
//
#include <hip/hip_runtime.h>
#include <hip/hip_bf16.h>
#include <stdint.h>

// MFMA fragment types (gfx950: mfma_f32_16x16x32_bf16 takes <8 x bf16>)
typedef __bf16 bf16x8 __attribute__((ext_vector_type(8)));
typedef float  f32x4  __attribute__((ext_vector_type(4)));

#define MFMA(A, B, C) __builtin_amdgcn_mfma_f32_16x16x32_bf16((A), (B), (C), 0, 0, 0)

// fp32 -> bf16 round-to-nearest-even
static __device__ __forceinline__ unsigned short f2b(float f) {
    union { float f; unsigned int u; } v; v.f = f;
    return (unsigned short)((v.u + 0x7FFFu + ((v.u >> 16) & 1u)) >> 16);
}

// ---------------------------------------------------------------------------
// Kernel 1: x fp32 -> bf16 [N+1][128]; zero pad row N of x_bf16 and h_comb.
// ---------------------------------------------------------------------------
__global__ __launch_bounds__(256) void convert_kernel(
    const float* __restrict__ x, unsigned short* __restrict__ xb,
    unsigned short* __restrict__ hb, int N) {
    long long i = (long long)blockIdx.x * blockDim.x + threadIdx.x; // 4 elems each
    long long base = i * 4;
    long long nx = (long long)N * 128;
    long long total = nx + 128;
    if (base >= total) return;
    if (base < nx) {
        float4 v = *(const float4*)(x + base);
        ushort4 o;
        o.x = f2b(v.x); o.y = f2b(v.y); o.z = f2b(v.z); o.w = f2b(v.w);
        *(ushort4*)(xb + base) = o;
    } else {
        ushort4 z = make_ushort4(0, 0, 0, 0);
        *(ushort4*)(xb + base) = z;   // pad row (index == N -> zeros)
        *(ushort4*)(hb + base) = z;
    }
}

// ---------------------------------------------------------------------------
// Kernel 2: pack weights into MFMA B-fragment order.
// Layout: wp[((s*4 + t)*64 + lane)*8 + j] = W[k][cinb + q*8 + j][t*16 + n16]
//   where q=lane>>4, n16=lane&15, k=s/cinSteps, cinb=(s%cinSteps)*32.
// ---------------------------------------------------------------------------
__global__ __launch_bounds__(256) void pack_kernel(
    const float* __restrict__ W00, const float* __restrict__ W01,
    const float* __restrict__ W10, const float* __restrict__ W11,
    const float* __restrict__ W12,
    unsigned short* __restrict__ wp00, unsigned short* __restrict__ wp01,
    unsigned short* __restrict__ wp10, unsigned short* __restrict__ wp11,
    unsigned short* __restrict__ wp12) {
    int g = blockIdx.x * blockDim.x + threadIdx.x;
    const float* W; unsigned short* out; int cinSteps;
    if (g < 27648)      { W = W00; out = wp00; cinSteps = 4; }
    else if (g < 41472) { g -= 27648; W = W01; out = wp01; cinSteps = 2; }
    else if (g < 55296) { g -= 41472; W = W11; out = wp11; cinSteps = 2; }
    else if (g < 56320) { g -= 55296; W = W10; out = wp10; cinSteps = 4; }
    else if (g < 56832) { g -= 56320; W = W12; out = wp12; cinSteps = 2; }
    else return;
    int lane = g & 63;
    int st   = g >> 6;
    int t    = st & 3;
    int s    = st >> 2;
    int q = lane >> 4, n16 = lane & 15;
    int k    = s / cinSteps;
    int cinb = (s % cinSteps) * 32;
    int Cin  = cinSteps * 32;
    int cout = t * 16 + n16;
    unsigned short o[8];
#pragma unroll
    for (int j = 0; j < 8; ++j) {
        float v = W[(size_t)(k * Cin + cinb + q * 8 + j) * 64 + cout];
        o[j] = f2b(v);
    }
    *(ushort4*)(out + (size_t)g * 8)     = make_ushort4(o[0], o[1], o[2], o[3]);
    *(ushort4*)(out + (size_t)g * 8 + 4) = make_ushort4(o[4], o[5], o[6], o[7]);
}

// ---------------------------------------------------------------------------
// Pass B: h0 = relu(sparse_conv(x, W00, b00)); h1 = relu(x @ W10 + b10)
// Writes h_comb[N][128] bf16 = [h0 | h1].
// One wave = 16 rows x 64 cout.  64 rows/block -> grid ~1563 for occupancy.
// Software pipeline: gather A(k+1) before MFMA(k); nbr index prefetched 2
// ahead. Final pipeline slot prefetches the wave's OWN row for the 1x1 conv.
// ---------------------------------------------------------------------------
__global__ __launch_bounds__(256, 4) void passB_kernel(
    const unsigned short* __restrict__ xb, const int* __restrict__ nbr,
    const unsigned short* __restrict__ wp00, const unsigned short* __restrict__ wp10,
    const float* __restrict__ b00, const float* __restrict__ b10,
    unsigned short* __restrict__ hb, int N) {
    int lane = threadIdx.x & 63;
    int wv   = threadIdx.x >> 6;
    int q = lane >> 4, n16 = lane & 15;
    int rowbase = blockIdx.x * 64 + wv * 16;

    f32x4 acc0[4];   // conv0_0 accum per n-tile
    f32x4 acc1[4];   // conv1_0 (1x1) accum
#pragma unroll
    for (int t = 0; t < 4; ++t) { acc0[t] = (f32x4)0.f; acc1[t] = (f32x4)0.f; }

    int mc = min(rowbase + n16, N - 1);   // A-row for this lane (lane&15)
    size_t nb = (size_t)mc * 27;
    int idx1 = nbr[nb];        // index for k=0
    int idx2 = nbr[nb + 1];    // index for k=1

    // preload A for k=0
    bf16x8 Ac[4];
    {
        const unsigned short* ap = xb + (size_t)idx1 * 128 + q * 8;
#pragma unroll
        for (int s2 = 0; s2 < 4; ++s2) Ac[s2] = *(const bf16x8*)(ap + s2 * 32);
    }
    idx1 = idx2;

    for (int k = 0; k < 27; ++k) {
        // prefetch index for k+2 (own row when past the end -> feeds 1x1 conv)
        int idxn = (k + 2 < 27) ? nbr[nb + k + 2] : mc;
        // prefetch A for k+1 (idx1); k=26 loads own row
        bf16x8 An[4];
        {
            const unsigned short* ap = xb + (size_t)idx1 * 128 + q * 8;
#pragma unroll
            for (int s2 = 0; s2 < 4; ++s2) An[s2] = *(const bf16x8*)(ap + s2 * 32);
        }
        const unsigned short* bp = wp00 + (size_t)k * 8192 + lane * 8;
#pragma unroll
        for (int s2 = 0; s2 < 4; ++s2)
#pragma unroll
            for (int t = 0; t < 4; ++t) {
                bf16x8 B = *(const bf16x8*)(bp + s2 * 2048 + t * 512);
                acc0[t] = MFMA(Ac[s2], B, acc0[t]);
            }
#pragma unroll
        for (int s2 = 0; s2 < 4; ++s2) Ac[s2] = An[s2];
        idx1 = idxn;
    }

    // fused 1x1 conv: Ac now holds the wave's own row
    {
        const unsigned short* bp = wp10 + lane * 8;
#pragma unroll
        for (int s2 = 0; s2 < 4; ++s2)
#pragma unroll
            for (int t = 0; t < 4; ++t) {
                bf16x8 B = *(const bf16x8*)(bp + s2 * 2048 + t * 512);
                acc1[t] = MFMA(Ac[s2], B, acc1[t]);
            }
    }

    // epilogue: bias, relu, -> bf16, store h_comb.  C-layout: col=lane&15, row=q*4+r
#pragma unroll
    for (int t = 0; t < 4; ++t) {
        int col = t * 16 + n16;
        float bb0 = b00[col], bb1 = b10[col];
#pragma unroll
        for (int r = 0; r < 4; ++r) {
            int row = rowbase + q * 4 + r;
            if (row < N) {
                hb[(size_t)row * 128 + col]      = f2b(fmaxf(acc0[t][r] + bb0, 0.f));
                hb[(size_t)row * 128 + 64 + col] = f2b(fmaxf(acc1[t][r] + bb1, 0.f));
            }
        }
    }
}

// ---------------------------------------------------------------------------
// Pass C: out0 = sparse_conv(h0, W01, b01);  t = relu(sparse_conv(h1, W11, b11));
//         out1 = t @ W12 + b12;  out = [out0 | out1] + x   (fp32)
// One gather of h_comb feeds both convs.  Same 16-rows/wave pipeline as pass B.
// ---------------------------------------------------------------------------
__global__ __launch_bounds__(256, 4) void passC_kernel(
    const unsigned short* __restrict__ hb, const int* __restrict__ nbr,
    const float* __restrict__ x,
    const unsigned short* __restrict__ wp01, const unsigned short* __restrict__ wp11,
    const unsigned short* __restrict__ wp12,
    const float* __restrict__ b01, const float* __restrict__ b11,
    const float* __restrict__ b12, float* __restrict__ out, int N) {
    // C-layout -> A-layout round trip for t.  stride 72 elems (144 B).
    __shared__ __align__(16) unsigned short lds[4 * 16 * 72];
    int lane = threadIdx.x & 63;
    int wv   = threadIdx.x >> 6;
    int q = lane >> 4, n16 = lane & 15;
    int rowbase = blockIdx.x * 64 + wv * 16;

    f32x4 accO0[4];  // out0 accum
    f32x4 accT[4];   // conv1_1 accum
#pragma unroll
    for (int t = 0; t < 4; ++t) { accO0[t] = (f32x4)0.f; accT[t] = (f32x4)0.f; }

    int mc = min(rowbase + n16, N - 1);
    size_t nb = (size_t)mc * 27;
    int idx1 = nbr[nb];
    int idx2 = nbr[nb + 1];

    bf16x8 Ac[2], Cc[2];   // h0-slice and h1-slice fragments
    {
        const unsigned short* g = hb + (size_t)idx1 * 128 + q * 8;
#pragma unroll
        for (int s2 = 0; s2 < 2; ++s2) {
            Ac[s2] = *(const bf16x8*)(g + s2 * 32);
            Cc[s2] = *(const bf16x8*)(g + 64 + s2 * 32);
        }
    }
    idx1 = idx2;

    for (int k = 0; k < 27; ++k) {
        int idxn = (k + 2 < 27) ? nbr[nb + k + 2] : N;   // N -> zero pad row
        bf16x8 An[2], Cn[2];
        {
            const unsigned short* g = hb + (size_t)idx1 * 128 + q * 8;
#pragma unroll
            for (int s2 = 0; s2 < 2; ++s2) {
                An[s2] = *(const bf16x8*)(g + s2 * 32);
                Cn[s2] = *(const bf16x8*)(g + 64 + s2 * 32);
            }
        }
#pragma unroll
        for (int s2 = 0; s2 < 2; ++s2) {
            const unsigned short* bp  = wp01 + (size_t)(k * 2 + s2) * 2048 + lane * 8;
            const unsigned short* bp2 = wp11 + (size_t)(k * 2 + s2) * 2048 + lane * 8;
#pragma unroll
            for (int t = 0; t < 4; ++t) {
                bf16x8 B = *(const bf16x8*)(bp + t * 512);
                accO0[t] = MFMA(Ac[s2], B, accO0[t]);
            }
#pragma unroll
            for (int t = 0; t < 4; ++t) {
                bf16x8 B2 = *(const bf16x8*)(bp2 + t * 512);
                accT[t] = MFMA(Cc[s2], B2, accT[t]);
            }
        }
#pragma unroll
        for (int s2 = 0; s2 < 2; ++s2) { Ac[s2] = An[s2]; Cc[s2] = Cn[s2]; }
        idx1 = idxn;
    }

    // epilogue 1: out0 (+bias +residual, fp32), and t -> relu -> bf16 -> LDS
    unsigned short* myl = lds + (size_t)wv * (16 * 72);
#pragma unroll
    for (int t = 0; t < 4; ++t) {
        int col = t * 16 + n16;
        float bo = b01[col], bt = b11[col];
#pragma unroll
        for (int r = 0; r < 4; ++r) {
            int row = rowbase + q * 4 + r;
            if (row < N)
                out[(size_t)row * 128 + col] =
                    accO0[t][r] + bo + x[(size_t)row * 128 + col];
            float tv = fmaxf(accT[t][r] + bt, 0.f);
            myl[(q * 4 + r) * 72 + col] = f2b(tv);
        }
    }
    __syncthreads();

    // mini-GEMM: out1 = relu(t) @ W12   (A from LDS in A-layout)
    f32x4 accO1[4];
#pragma unroll
    for (int t = 0; t < 4; ++t) accO1[t] = (f32x4)0.f;
#pragma unroll
    for (int s2 = 0; s2 < 2; ++s2) {
        bf16x8 A = *(const bf16x8*)(myl + n16 * 72 + s2 * 32 + q * 8);
        const unsigned short* bp = wp12 + (size_t)s2 * 2048 + lane * 8;
#pragma unroll
        for (int t = 0; t < 4; ++t) {
            bf16x8 B = *(const bf16x8*)(bp + t * 512);
            accO1[t] = MFMA(A, B, accO1[t]);
        }
    }
#pragma unroll
    for (int t = 0; t < 4; ++t) {
        int col = t * 16 + n16;
        float bo = b12[col];
#pragma unroll
        for (int r = 0; r < 4; ++r) {
            int row = rowbase + q * 4 + r;
            if (row < N)
                out[(size_t)row * 128 + 64 + col] =
                    accO1[t][r] + bo + x[(size_t)row * 128 + 64 + col];
        }
    }
}

// ---------------------------------------------------------------------------
extern "C" void kernel_launch(void* const* d_in, const int* in_sizes, int n_in,
                              void* d_out, int out_size, void* d_ws, size_t ws_size,
                              hipStream_t stream) {
    const float* x   = (const float*)d_in[0];
    const int*   nbr = (const int*)d_in[1];
    const float* W00 = (const float*)d_in[2];
    const float* b00 = (const float*)d_in[3];
    const float* W01 = (const float*)d_in[4];
    const float* b01 = (const float*)d_in[5];
    const float* W10 = (const float*)d_in[6];
    const float* b10 = (const float*)d_in[7];
    const float* W11 = (const float*)d_in[8];
    const float* b11 = (const float*)d_in[9];
    const float* W12 = (const float*)d_in[10];
    const float* b12 = (const float*)d_in[11];
    float* out = (float*)d_out;
    int N = in_sizes[0] / 128;   // 100000

    // workspace carve-up
    char* ws = (char*)d_ws;
    size_t cur = 0;
    unsigned short* xb = (unsigned short*)(ws + cur); cur += (size_t)(N + 1) * 128 * 2;
    unsigned short* hb = (unsigned short*)(ws + cur); cur += (size_t)(N + 1) * 128 * 2;
    unsigned short* wp00 = (unsigned short*)(ws + cur); cur += 27648 * 8 * 2;
    unsigned short* wp01 = (unsigned short*)(ws + cur); cur += 13824 * 8 * 2;
    unsigned short* wp11 = (unsigned short*)(ws + cur); cur += 13824 * 8 * 2;
    unsigned short* wp10 = (unsigned short*)(ws + cur); cur += 1024 * 8 * 2;
    unsigned short* wp12 = (unsigned short*)(ws + cur); cur += 512 * 8 * 2;

    long long cvt_groups = ((long long)N * 128 + 128) / 4;
    int cvt_blocks = (int)((cvt_groups + 255) / 256);
    convert_kernel<<<cvt_blocks, 256, 0, stream>>>(x, xb, hb, N);
    pack_kernel<<<222, 256, 0, stream>>>(W00, W01, W10, W11, W12,
                                         wp00, wp01, wp10, wp11, wp12);
    int blocks = (N + 63) / 64;
    passB_kernel<<<blocks, 256, 0, stream>>>(xb, nbr, wp00, wp10, b00, b10, hb, N);
    passC_kernel<<<blocks, 256, 0, stream>>>(hb, nbr, x, wp01, wp11, wp12,
                                             b01, b11, b12, out, N);
}

// Round 3
// 437.756 us; speedup vs baseline: 1.2176x; 1.2176x over previous
//
#include <hip/hip_runtime.h>
#include <hip/hip_bf16.h>
#include <stdint.h>

// MFMA fragment types (gfx950: mfma_f32_16x16x32_bf16 takes <8 x bf16>)
typedef __bf16 bf16x8 __attribute__((ext_vector_type(8)));
typedef float  f32x4  __attribute__((ext_vector_type(4)));

#define MFMA(A, B, C) __builtin_amdgcn_mfma_f32_16x16x32_bf16((A), (B), (C), 0, 0, 0)

// fp32 -> bf16 round-to-nearest-even
static __device__ __forceinline__ unsigned short f2b(float f) {
    union { float f; unsigned int u; } v; v.f = f;
    return (unsigned short)((v.u + 0x7FFFu + ((v.u >> 16) & 1u)) >> 16);
}

// ---------------------------------------------------------------------------
// Kernel 1: x fp32 -> bf16 [N+1][128]; zero pad row N of x_bf16 and h_comb.
// ---------------------------------------------------------------------------
__global__ __launch_bounds__(256) void convert_kernel(
    const float* __restrict__ x, unsigned short* __restrict__ xb,
    unsigned short* __restrict__ hb, int N) {
    long long i = (long long)blockIdx.x * blockDim.x + threadIdx.x; // 4 elems each
    long long base = i * 4;
    long long nx = (long long)N * 128;
    long long total = nx + 128;
    if (base >= total) return;
    if (base < nx) {
        float4 v = *(const float4*)(x + base);
        ushort4 o;
        o.x = f2b(v.x); o.y = f2b(v.y); o.z = f2b(v.z); o.w = f2b(v.w);
        *(ushort4*)(xb + base) = o;
    } else {
        ushort4 z = make_ushort4(0, 0, 0, 0);
        *(ushort4*)(xb + base) = z;   // pad row (index == N -> zeros)
        *(ushort4*)(hb + base) = z;
    }
}

// ---------------------------------------------------------------------------
// Kernel 2: pack weights into MFMA B-fragment order.
// wp00: per-k contiguous 16KB slices (k*8192 + (s2*4+t)*512 + lane*8).
// wpC : conv01 and conv11 k-slices interleaved: k*8192 + [0|4096] + ...
//       so one contiguous 16KB load per k feeds BOTH passC convs.
// ---------------------------------------------------------------------------
__global__ __launch_bounds__(256) void pack_kernel(
    const float* __restrict__ W00, const float* __restrict__ W01,
    const float* __restrict__ W10, const float* __restrict__ W11,
    const float* __restrict__ W12,
    unsigned short* __restrict__ wp00, unsigned short* __restrict__ wpC,
    unsigned short* __restrict__ wp10, unsigned short* __restrict__ wp12) {
    int g = blockIdx.x * blockDim.x + threadIdx.x;
    const float* W; int cinSteps; int which;
    if (g < 27648)      { W = W00; cinSteps = 4; which = 0; }
    else if (g < 41472) { g -= 27648; W = W01; cinSteps = 2; which = 1; }
    else if (g < 55296) { g -= 41472; W = W11; cinSteps = 2; which = 2; }
    else if (g < 56320) { g -= 55296; W = W10; cinSteps = 4; which = 3; }
    else if (g < 56832) { g -= 56320; W = W12; cinSteps = 2; which = 4; }
    else return;
    int lane = g & 63;
    int st   = g >> 6;
    int t    = st & 3;
    int s    = st >> 2;
    int q = lane >> 4, n16 = lane & 15;
    int k    = s / cinSteps;
    int cinb = (s % cinSteps) * 32;
    int Cin  = cinSteps * 32;
    int cout = t * 16 + n16;
    unsigned short o[8];
#pragma unroll
    for (int j = 0; j < 8; ++j) {
        float v = W[(size_t)(k * Cin + cinb + q * 8 + j) * 64 + cout];
        o[j] = f2b(v);
    }
    unsigned short* dst;
    if (which == 0)      dst = wp00 + (size_t)g * 8;
    else if (which == 1) dst = wpC + (size_t)k * 8192 +
                               ((size_t)(((s & 1) * 4 + t) * 64 + lane)) * 8;
    else if (which == 2) dst = wpC + (size_t)k * 8192 + 4096 +
                               ((size_t)(((s & 1) * 4 + t) * 64 + lane)) * 8;
    else if (which == 3) dst = wp10 + (size_t)g * 8;
    else                 dst = wp12 + (size_t)g * 8;
    *(ushort4*)(dst)     = make_ushort4(o[0], o[1], o[2], o[3]);
    *(ushort4*)(dst + 4) = make_ushort4(o[4], o[5], o[6], o[7]);
}

// ---------------------------------------------------------------------------
// Pass B: h0 = relu(sparse_conv(x, W00, b00)); h1 = relu(x @ W10 + b10)
// 32 rows/wave, 128 rows/block.  B-slice (16KB/k) staged in LDS once per
// block, double-buffered, shared by 4 waves (cuts B global traffic 4x).
// Gathers prefetched 1 iter ahead; last prefetch slot = own row -> 1x1 conv.
// ---------------------------------------------------------------------------
__global__ __launch_bounds__(256, 2) void passB_kernel(
    const unsigned short* __restrict__ xb, const int* __restrict__ nbr,
    const unsigned short* __restrict__ wp00, const unsigned short* __restrict__ wp10,
    const float* __restrict__ b00, const float* __restrict__ b10,
    unsigned short* __restrict__ hb, int N) {
    __shared__ __align__(16) unsigned short bbuf[2][8192];
    int tid = threadIdx.x;
    int lane = tid & 63;
    int wv   = tid >> 6;
    int q = lane >> 4, n16 = lane & 15;
    int rowbase = blockIdx.x * 128 + wv * 32;

    f32x4 acc0[2][4];   // conv0_0 accum [rowset][t]
    f32x4 acc1[2][4];   // conv1_0 (1x1) accum
#pragma unroll
    for (int rs = 0; rs < 2; ++rs)
#pragma unroll
        for (int t = 0; t < 4; ++t) { acc0[rs][t] = (f32x4)0.f; acc1[rs][t] = (f32x4)0.f; }

    int mc0 = min(rowbase + n16, N - 1);
    int mc1 = min(rowbase + 16 + n16, N - 1);
    size_t nb0 = (size_t)mc0 * 27, nb1 = (size_t)mc1 * 27;

    int ia = nbr[nb0], ib = nbr[nb1];          // idx(0)
    // B(0) -> regs
    int4 br[4];
#pragma unroll
    for (int j = 0; j < 4; ++j) br[j] = *(const int4*)(wp00 + j * 2048 + tid * 8);
    // gather(0)
    bf16x8 A0c[4], A1c[4];
    {
        const unsigned short* p0 = xb + (size_t)ia * 128 + q * 8;
        const unsigned short* p1 = xb + (size_t)ib * 128 + q * 8;
#pragma unroll
        for (int s2 = 0; s2 < 4; ++s2) {
            A0c[s2] = *(const bf16x8*)(p0 + s2 * 32);
            A1c[s2] = *(const bf16x8*)(p1 + s2 * 32);
        }
    }
    int ian = nbr[nb0 + 1], ibn = nbr[nb1 + 1];   // idx(1)
#pragma unroll
    for (int j = 0; j < 4; ++j) *(int4*)(&bbuf[0][j * 2048 + tid * 8]) = br[j];
    __syncthreads();

    for (int k = 0; k < 27; ++k) {
        int buf = k & 1;
        if (k < 26) {   // B(k+1) global -> regs
            const unsigned short* src = wp00 + (size_t)(k + 1) * 8192;
#pragma unroll
            for (int j = 0; j < 4; ++j) br[j] = *(const int4*)(src + j * 2048 + tid * 8);
        }
        // idx(k+2); past end -> own row (feeds the fused 1x1 conv)
        int ia2 = (k + 2 < 27) ? nbr[nb0 + k + 2] : mc0;
        int ib2 = (k + 2 < 27) ? nbr[nb1 + k + 2] : mc1;
        // gather(k+1)
        bf16x8 A0n[4], A1n[4];
        {
            const unsigned short* p0 = xb + (size_t)ian * 128 + q * 8;
            const unsigned short* p1 = xb + (size_t)ibn * 128 + q * 8;
#pragma unroll
            for (int s2 = 0; s2 < 4; ++s2) {
                A0n[s2] = *(const bf16x8*)(p0 + s2 * 32);
                A1n[s2] = *(const bf16x8*)(p1 + s2 * 32);
            }
        }
        // MFMA on B(k) from LDS
        const unsigned short* lb = &bbuf[buf][0];
#pragma unroll
        for (int s2 = 0; s2 < 4; ++s2)
#pragma unroll
            for (int t = 0; t < 4; ++t) {
                bf16x8 B = *(const bf16x8*)(lb + (s2 * 4 + t) * 512 + lane * 8);
                acc0[0][t] = MFMA(A0c[s2], B, acc0[0][t]);
                acc0[1][t] = MFMA(A1c[s2], B, acc0[1][t]);
            }
        if (k < 26) {
#pragma unroll
            for (int j = 0; j < 4; ++j)
                *(int4*)(&bbuf[buf ^ 1][j * 2048 + tid * 8]) = br[j];
        }
#pragma unroll
        for (int s2 = 0; s2 < 4; ++s2) { A0c[s2] = A0n[s2]; A1c[s2] = A1n[s2]; }
        ian = ia2; ibn = ib2;
        __syncthreads();
    }

    // fused 1x1 conv: A0c/A1c now hold the wave's own rows
#pragma unroll
    for (int s2 = 0; s2 < 4; ++s2)
#pragma unroll
        for (int t = 0; t < 4; ++t) {
            bf16x8 B = *(const bf16x8*)(wp10 + s2 * 2048 + t * 512 + lane * 8);
            acc1[0][t] = MFMA(A0c[s2], B, acc1[0][t]);
            acc1[1][t] = MFMA(A1c[s2], B, acc1[1][t]);
        }

    // epilogue: bias, relu, -> bf16, store h_comb.  C-layout: col=lane&15, row=q*4+r
#pragma unroll
    for (int rs = 0; rs < 2; ++rs)
#pragma unroll
        for (int t = 0; t < 4; ++t) {
            int col = t * 16 + n16;
            float bb0 = b00[col], bb1 = b10[col];
#pragma unroll
            for (int r = 0; r < 4; ++r) {
                int row = rowbase + rs * 16 + q * 4 + r;
                if (row < N) {
                    hb[(size_t)row * 128 + col]      = f2b(fmaxf(acc0[rs][t][r] + bb0, 0.f));
                    hb[(size_t)row * 128 + 64 + col] = f2b(fmaxf(acc1[rs][t][r] + bb1, 0.f));
                }
            }
        }
}

// ---------------------------------------------------------------------------
// Pass C: out0 = sparse_conv(h0, W01, b01);  t = relu(sparse_conv(h1, W11, b11));
//         out1 = t @ W12 + b12;  out = [out0 | out1] + x  (fp32)
// Same LDS B double-buffer (wpC has both convs' slices back-to-back per k).
// One gather of h_comb feeds both convs.  Residual/out use nontemporal ops.
// ---------------------------------------------------------------------------
__global__ __launch_bounds__(256, 2) void passC_kernel(
    const unsigned short* __restrict__ hb, const int* __restrict__ nbr,
    const float* __restrict__ x,
    const unsigned short* __restrict__ wpC, const unsigned short* __restrict__ wp12,
    const float* __restrict__ b01, const float* __restrict__ b11,
    const float* __restrict__ b12, float* __restrict__ out, int N) {
    __shared__ __align__(16) unsigned short bbuf[2][8192];
    int tid = threadIdx.x;
    int lane = tid & 63;
    int wv   = tid >> 6;
    int q = lane >> 4, n16 = lane & 15;
    int rowbase = blockIdx.x * 128 + wv * 32;

    f32x4 accO0[2][4];
    f32x4 accT[2][4];
#pragma unroll
    for (int rs = 0; rs < 2; ++rs)
#pragma unroll
        for (int t = 0; t < 4; ++t) { accO0[rs][t] = (f32x4)0.f; accT[rs][t] = (f32x4)0.f; }

    int mc0 = min(rowbase + n16, N - 1);
    int mc1 = min(rowbase + 16 + n16, N - 1);
    size_t nb0 = (size_t)mc0 * 27, nb1 = (size_t)mc1 * 27;

    int ia = nbr[nb0], ib = nbr[nb1];
    int4 br[4];
#pragma unroll
    for (int j = 0; j < 4; ++j) br[j] = *(const int4*)(wpC + j * 2048 + tid * 8);
    bf16x8 A0c[2], C0c[2], A1c[2], C1c[2];
    {
        const unsigned short* p0 = hb + (size_t)ia * 128 + q * 8;
        const unsigned short* p1 = hb + (size_t)ib * 128 + q * 8;
#pragma unroll
        for (int s2 = 0; s2 < 2; ++s2) {
            A0c[s2] = *(const bf16x8*)(p0 + s2 * 32);
            C0c[s2] = *(const bf16x8*)(p0 + 64 + s2 * 32);
            A1c[s2] = *(const bf16x8*)(p1 + s2 * 32);
            C1c[s2] = *(const bf16x8*)(p1 + 64 + s2 * 32);
        }
    }
    int ian = nbr[nb0 + 1], ibn = nbr[nb1 + 1];
#pragma unroll
    for (int j = 0; j < 4; ++j) *(int4*)(&bbuf[0][j * 2048 + tid * 8]) = br[j];
    __syncthreads();

    for (int k = 0; k < 27; ++k) {
        int buf = k & 1;
        if (k < 26) {
            const unsigned short* src = wpC + (size_t)(k + 1) * 8192;
#pragma unroll
            for (int j = 0; j < 4; ++j) br[j] = *(const int4*)(src + j * 2048 + tid * 8);
        }
        int ia2 = (k + 2 < 27) ? nbr[nb0 + k + 2] : N;   // N -> zero pad row
        int ib2 = (k + 2 < 27) ? nbr[nb1 + k + 2] : N;
        bf16x8 A0n[2], C0n[2], A1n[2], C1n[2];
        {
            const unsigned short* p0 = hb + (size_t)ian * 128 + q * 8;
            const unsigned short* p1 = hb + (size_t)ibn * 128 + q * 8;
#pragma unroll
            for (int s2 = 0; s2 < 2; ++s2) {
                A0n[s2] = *(const bf16x8*)(p0 + s2 * 32);
                C0n[s2] = *(const bf16x8*)(p0 + 64 + s2 * 32);
                A1n[s2] = *(const bf16x8*)(p1 + s2 * 32);
                C1n[s2] = *(const bf16x8*)(p1 + 64 + s2 * 32);
            }
        }
        const unsigned short* lb = &bbuf[buf][0];
#pragma unroll
        for (int s2 = 0; s2 < 2; ++s2) {
#pragma unroll
            for (int t = 0; t < 4; ++t) {
                bf16x8 B = *(const bf16x8*)(lb + (s2 * 4 + t) * 512 + lane * 8);
                accO0[0][t] = MFMA(A0c[s2], B, accO0[0][t]);
                accO0[1][t] = MFMA(A1c[s2], B, accO0[1][t]);
            }
#pragma unroll
            for (int t = 0; t < 4; ++t) {
                bf16x8 B2 = *(const bf16x8*)(lb + 4096 + (s2 * 4 + t) * 512 + lane * 8);
                accT[0][t] = MFMA(C0c[s2], B2, accT[0][t]);
                accT[1][t] = MFMA(C1c[s2], B2, accT[1][t]);
            }
        }
        if (k < 26) {
#pragma unroll
            for (int j = 0; j < 4; ++j)
                *(int4*)(&bbuf[buf ^ 1][j * 2048 + tid * 8]) = br[j];
        }
#pragma unroll
        for (int s2 = 0; s2 < 2; ++s2) {
            A0c[s2] = A0n[s2]; C0c[s2] = C0n[s2];
            A1c[s2] = A1n[s2]; C1c[s2] = C1n[s2];
        }
        ian = ia2; ibn = ib2;
        __syncthreads();   // final barrier also guards scratch reuse below
    }

    // epilogue 1: out0 (+bias +residual), t -> relu -> bf16 -> LDS scratch
    unsigned short* scratch = &bbuf[0][0];            // reuse B buffers
    unsigned short* myl = scratch + wv * 2304;        // 32 rows x 72 per wave
#pragma unroll
    for (int rs = 0; rs < 2; ++rs)
#pragma unroll
        for (int t = 0; t < 4; ++t) {
            int col = t * 16 + n16;
            float bo = b01[col], bt = b11[col];
#pragma unroll
            for (int r = 0; r < 4; ++r) {
                int row = rowbase + rs * 16 + q * 4 + r;
                if (row < N) {
                    float xv = __builtin_nontemporal_load(x + (size_t)row * 128 + col);
                    __builtin_nontemporal_store(accO0[rs][t][r] + bo + xv,
                                                out + (size_t)row * 128 + col);
                }
                float tv = fmaxf(accT[rs][t][r] + bt, 0.f);
                myl[(rs * 16 + q * 4 + r) * 72 + col] = f2b(tv);
            }
        }
    // per-wave private region: within-wave lgkmcnt ordering suffices (no barrier)

    // mini-GEMM: out1 = relu(t) @ W12
    f32x4 accO1[2][4];
#pragma unroll
    for (int rs = 0; rs < 2; ++rs)
#pragma unroll
        for (int t = 0; t < 4; ++t) accO1[rs][t] = (f32x4)0.f;
#pragma unroll
    for (int s2 = 0; s2 < 2; ++s2) {
        bf16x8 A0 = *(const bf16x8*)(myl + n16 * 72 + s2 * 32 + q * 8);
        bf16x8 A1 = *(const bf16x8*)(myl + (16 + n16) * 72 + s2 * 32 + q * 8);
#pragma unroll
        for (int t = 0; t < 4; ++t) {
            bf16x8 B = *(const bf16x8*)(wp12 + s2 * 2048 + t * 512 + lane * 8);
            accO1[0][t] = MFMA(A0, B, accO1[0][t]);
            accO1[1][t] = MFMA(A1, B, accO1[1][t]);
        }
    }
#pragma unroll
    for (int rs = 0; rs < 2; ++rs)
#pragma unroll
        for (int t = 0; t < 4; ++t) {
            int col = t * 16 + n16;
            float bo = b12[col];
#pragma unroll
            for (int r = 0; r < 4; ++r) {
                int row = rowbase + rs * 16 + q * 4 + r;
                if (row < N) {
                    float xv = __builtin_nontemporal_load(x + (size_t)row * 128 + 64 + col);
                    __builtin_nontemporal_store(accO1[rs][t][r] + bo + xv,
                                                out + (size_t)row * 128 + 64 + col);
                }
            }
        }
}

// ---------------------------------------------------------------------------
extern "C" void kernel_launch(void* const* d_in, const int* in_sizes, int n_in,
                              void* d_out, int out_size, void* d_ws, size_t ws_size,
                              hipStream_t stream) {
    const float* x   = (const float*)d_in[0];
    const int*   nbr = (const int*)d_in[1];
    const float* W00 = (const float*)d_in[2];
    const float* b00 = (const float*)d_in[3];
    const float* W01 = (const float*)d_in[4];
    const float* b01 = (const float*)d_in[5];
    const float* W10 = (const float*)d_in[6];
    const float* b10 = (const float*)d_in[7];
    const float* W11 = (const float*)d_in[8];
    const float* b11 = (const float*)d_in[9];
    const float* W12 = (const float*)d_in[10];
    const float* b12 = (const float*)d_in[11];
    float* out = (float*)d_out;
    int N = in_sizes[0] / 128;   // 100000

    // workspace carve-up
    char* ws = (char*)d_ws;
    size_t cur = 0;
    unsigned short* xb  = (unsigned short*)(ws + cur); cur += (size_t)(N + 1) * 128 * 2;
    unsigned short* hb  = (unsigned short*)(ws + cur); cur += (size_t)(N + 1) * 128 * 2;
    unsigned short* wp00 = (unsigned short*)(ws + cur); cur += 27648 * 8 * 2;
    unsigned short* wpC  = (unsigned short*)(ws + cur); cur += (size_t)27 * 8192 * 2;
    unsigned short* wp10 = (unsigned short*)(ws + cur); cur += 8192 * 2;
    unsigned short* wp12 = (unsigned short*)(ws + cur); cur += 4096 * 2;

    long long cvt_groups = ((long long)N * 128 + 128) / 4;
    int cvt_blocks = (int)((cvt_groups + 255) / 256);
    convert_kernel<<<cvt_blocks, 256, 0, stream>>>(x, xb, hb, N);
    pack_kernel<<<222, 256, 0, stream>>>(W00, W01, W10, W11, W12,
                                         wp00, wpC, wp10, wp12);
    int blocks = (N + 127) / 128;   // 782 blocks, 128 rows each
    passB_kernel<<<blocks, 256, 0, stream>>>(xb, nbr, wp00, wp10, b00, b10, hb, N);
    passC_kernel<<<blocks, 256, 0, stream>>>(hb, nbr, x, wpC, wp12,
                                             b01, b11, b12, out, N);
}

// Round 4
// 414.290 us; speedup vs baseline: 1.2866x; 1.0566x over previous
//
#include <hip/hip_runtime.h>
#include <hip/hip_bf16.h>
#include <stdint.h>

// MFMA fragment types (gfx950: mfma_f32_16x16x32_bf16 takes <8 x bf16>)
typedef __bf16 bf16x8 __attribute__((ext_vector_type(8)));
typedef float  f32x4  __attribute__((ext_vector_type(4)));

#define MFMA(A, B, C) __builtin_amdgcn_mfma_f32_16x16x32_bf16((A), (B), (C), 0, 0, 0)

// fp32 -> bf16 round-to-nearest-even
static __device__ __forceinline__ unsigned short f2b(float f) {
    union { float f; unsigned int u; } v; v.f = f;
    return (unsigned short)((v.u + 0x7FFFu + ((v.u >> 16) & 1u)) >> 16);
}

// Redistribute a coalesced-gathered 16B fragment to MFMA A-layout.
// Gather layout: lane l holds row (l>>2), 16B chunk (l&3) of a 64B k-block.
// MFMA wants lane j = m + 16q to hold row m, chunk q -> pull from lane 4m+q.
static __device__ __forceinline__ bf16x8 perm_frag(int sel, bf16x8 D) {
    union { bf16x8 v; int d[4]; } u, r;
    u.v = D;
#pragma unroll
    for (int w = 0; w < 4; ++w) r.d[w] = __builtin_amdgcn_ds_bpermute(sel, u.d[w]);
    return r.v;
}

// ---------------------------------------------------------------------------
// Kernel 1: x fp32 -> bf16 [N+1][128]; zero pad row N of x_bf16 and h_comb.
// ---------------------------------------------------------------------------
__global__ __launch_bounds__(256) void convert_kernel(
    const float* __restrict__ x, unsigned short* __restrict__ xb,
    unsigned short* __restrict__ hb, int N) {
    long long i = (long long)blockIdx.x * blockDim.x + threadIdx.x; // 4 elems each
    long long base = i * 4;
    long long nx = (long long)N * 128;
    long long total = nx + 128;
    if (base >= total) return;
    if (base < nx) {
        float4 v = *(const float4*)(x + base);
        ushort4 o;
        o.x = f2b(v.x); o.y = f2b(v.y); o.z = f2b(v.z); o.w = f2b(v.w);
        *(ushort4*)(xb + base) = o;
    } else {
        ushort4 z = make_ushort4(0, 0, 0, 0);
        *(ushort4*)(xb + base) = z;   // pad row (index == N -> zeros)
        *(ushort4*)(hb + base) = z;
    }
}

// ---------------------------------------------------------------------------
// Kernel 2: pack weights into MFMA B-fragment order.
// wp00: per-k contiguous 16KB slices (k*8192 + (s2*4+t)*512 + lane*8).
// wpC : conv01 and conv11 k-slices interleaved: k*8192 + [0|4096] + ...
// ---------------------------------------------------------------------------
__global__ __launch_bounds__(256) void pack_kernel(
    const float* __restrict__ W00, const float* __restrict__ W01,
    const float* __restrict__ W10, const float* __restrict__ W11,
    const float* __restrict__ W12,
    unsigned short* __restrict__ wp00, unsigned short* __restrict__ wpC,
    unsigned short* __restrict__ wp10, unsigned short* __restrict__ wp12) {
    int g = blockIdx.x * blockDim.x + threadIdx.x;
    const float* W; int cinSteps; int which;
    if (g < 27648)      { W = W00; cinSteps = 4; which = 0; }
    else if (g < 41472) { g -= 27648; W = W01; cinSteps = 2; which = 1; }
    else if (g < 55296) { g -= 41472; W = W11; cinSteps = 2; which = 2; }
    else if (g < 56320) { g -= 55296; W = W10; cinSteps = 4; which = 3; }
    else if (g < 56832) { g -= 56320; W = W12; cinSteps = 2; which = 4; }
    else return;
    int lane = g & 63;
    int st   = g >> 6;
    int t    = st & 3;
    int s    = st >> 2;
    int q = lane >> 4, n16 = lane & 15;
    int k    = s / cinSteps;
    int cinb = (s % cinSteps) * 32;
    int Cin  = cinSteps * 32;
    int cout = t * 16 + n16;
    unsigned short o[8];
#pragma unroll
    for (int j = 0; j < 8; ++j) {
        float v = W[(size_t)(k * Cin + cinb + q * 8 + j) * 64 + cout];
        o[j] = f2b(v);
    }
    unsigned short* dst;
    if (which == 0)      dst = wp00 + (size_t)g * 8;
    else if (which == 1) dst = wpC + (size_t)k * 8192 +
                               ((size_t)(((s & 1) * 4 + t) * 64 + lane)) * 8;
    else if (which == 2) dst = wpC + (size_t)k * 8192 + 4096 +
                               ((size_t)(((s & 1) * 4 + t) * 64 + lane)) * 8;
    else if (which == 3) dst = wp10 + (size_t)g * 8;
    else                 dst = wp12 + (size_t)g * 8;
    *(ushort4*)(dst)     = make_ushort4(o[0], o[1], o[2], o[3]);
    *(ushort4*)(dst + 4) = make_ushort4(o[4], o[5], o[6], o[7]);
}

// ---------------------------------------------------------------------------
// Pass B: h0 = relu(sparse_conv(x, W00, b00)); h1 = relu(x @ W10 + b10)
// 32 rows/wave, 128 rows/block.  B staged in LDS (double-buffered).
// Gathers are quarter-wave coalesced (lane l -> row l>>2, chunk l&3) and
// redistributed to MFMA A-layout via ds_bpermute at consumption time.
// nbr indices for the whole block staged in LDS once (coalesced).
// ---------------------------------------------------------------------------
__global__ __launch_bounds__(256, 2) void passB_kernel(
    const unsigned short* __restrict__ xb, const int* __restrict__ nbr,
    const unsigned short* __restrict__ wp00, const unsigned short* __restrict__ wp10,
    const float* __restrict__ b00, const float* __restrict__ b10,
    unsigned short* __restrict__ hb, int N) {
    __shared__ __align__(16) unsigned short bbuf[2][8192];
    __shared__ int lds_idx[128 * 27];
    int tid = threadIdx.x;
    int lane = tid & 63;
    int wv   = tid >> 6;
    int q = lane >> 4, n16 = lane & 15;
    int rowq = lane >> 2, chunk = lane & 3;
    int sel = (n16 * 4 + q) * 4;            // bpermute byte index
    int rowbase = blockIdx.x * 128 + wv * 32;

    // stage block's nbr slice (13.8 KB, coalesced) + B(0)
    {
        long long gbase = (long long)blockIdx.x * 128 * 27;
        long long lim = (long long)N * 27 - 1;
        for (int i = tid; i < 3456; i += 256) {
            long long gi = gbase + i; if (gi > lim) gi = lim;
            lds_idx[i] = nbr[gi];
        }
    }
    int4 br[4];
#pragma unroll
    for (int j = 0; j < 4; ++j) br[j] = *(const int4*)(wp00 + j * 2048 + tid * 8);
#pragma unroll
    for (int j = 0; j < 4; ++j) *(int4*)(&bbuf[0][j * 2048 + tid * 8]) = br[j];
    __syncthreads();

    f32x4 acc0[2][4];   // conv0_0 accum [rowset][t]
    f32x4 acc1[2][4];   // conv1_0 (1x1) accum
#pragma unroll
    for (int rs = 0; rs < 2; ++rs)
#pragma unroll
        for (int t = 0; t < 4; ++t) { acc0[rs][t] = (f32x4)0.f; acc1[rs][t] = (f32x4)0.f; }

    int idxb0 = (wv * 32 + rowq) * 27;          // rowset 0, this lane's row
    int idxb1 = (wv * 32 + 16 + rowq) * 27;     // rowset 1
    int own0 = min(rowbase + rowq, N - 1);      // own rows (coalesced mapping)
    int own1 = min(rowbase + 16 + rowq, N - 1);

    // raw gather D(0)
    int ia = lds_idx[idxb0], ib = lds_idx[idxb1];
    bf16x8 D0[4], D1[4];
    {
        const unsigned short* p0 = xb + (size_t)ia * 128 + chunk * 8;
        const unsigned short* p1 = xb + (size_t)ib * 128 + chunk * 8;
#pragma unroll
        for (int s2 = 0; s2 < 4; ++s2) {
            D0[s2] = *(const bf16x8*)(p0 + s2 * 32);
            D1[s2] = *(const bf16x8*)(p1 + s2 * 32);
        }
    }

    for (int k = 0; k < 27; ++k) {
        int buf = k & 1;
        if (k < 26) {   // B(k+1) global -> regs
            const unsigned short* src = wp00 + (size_t)(k + 1) * 8192;
#pragma unroll
            for (int j = 0; j < 4; ++j) br[j] = *(const int4*)(src + j * 2048 + tid * 8);
        }
        // next gather: idx(k+1) from LDS; past end -> own row (feeds 1x1 conv)
        int ian = (k + 1 < 27) ? lds_idx[idxb0 + k + 1] : own0;
        int ibn = (k + 1 < 27) ? lds_idx[idxb1 + k + 1] : own1;
        bf16x8 D0n[4], D1n[4];
        {
            const unsigned short* p0 = xb + (size_t)ian * 128 + chunk * 8;
            const unsigned short* p1 = xb + (size_t)ibn * 128 + chunk * 8;
#pragma unroll
            for (int s2 = 0; s2 < 4; ++s2) {
                D0n[s2] = *(const bf16x8*)(p0 + s2 * 32);
                D1n[s2] = *(const bf16x8*)(p1 + s2 * 32);
            }
        }
        // redistribute D(k) to MFMA layout, then MFMA with LDS B(k)
        const unsigned short* lb = &bbuf[buf][0];
#pragma unroll
        for (int s2 = 0; s2 < 4; ++s2) {
            bf16x8 A0 = perm_frag(sel, D0[s2]);
            bf16x8 A1 = perm_frag(sel, D1[s2]);
#pragma unroll
            for (int t = 0; t < 4; ++t) {
                bf16x8 B = *(const bf16x8*)(lb + (s2 * 4 + t) * 512 + lane * 8);
                acc0[0][t] = MFMA(A0, B, acc0[0][t]);
                acc0[1][t] = MFMA(A1, B, acc0[1][t]);
            }
        }
        if (k < 26) {
#pragma unroll
            for (int j = 0; j < 4; ++j)
                *(int4*)(&bbuf[buf ^ 1][j * 2048 + tid * 8]) = br[j];
        }
#pragma unroll
        for (int s2 = 0; s2 < 4; ++s2) { D0[s2] = D0n[s2]; D1[s2] = D1n[s2]; }
        __syncthreads();
    }

    // fused 1x1 conv: D now holds the wave's own rows
#pragma unroll
    for (int s2 = 0; s2 < 4; ++s2) {
        bf16x8 A0 = perm_frag(sel, D0[s2]);
        bf16x8 A1 = perm_frag(sel, D1[s2]);
#pragma unroll
        for (int t = 0; t < 4; ++t) {
            bf16x8 B = *(const bf16x8*)(wp10 + s2 * 2048 + t * 512 + lane * 8);
            acc1[0][t] = MFMA(A0, B, acc1[0][t]);
            acc1[1][t] = MFMA(A1, B, acc1[1][t]);
        }
    }

    // epilogue: bias, relu, -> bf16, store h_comb.  C-layout: col=lane&15, row=q*4+r
#pragma unroll
    for (int rs = 0; rs < 2; ++rs)
#pragma unroll
        for (int t = 0; t < 4; ++t) {
            int col = t * 16 + n16;
            float bb0 = b00[col], bb1 = b10[col];
#pragma unroll
            for (int r = 0; r < 4; ++r) {
                int row = rowbase + rs * 16 + q * 4 + r;
                if (row < N) {
                    hb[(size_t)row * 128 + col]      = f2b(fmaxf(acc0[rs][t][r] + bb0, 0.f));
                    hb[(size_t)row * 128 + 64 + col] = f2b(fmaxf(acc1[rs][t][r] + bb1, 0.f));
                }
            }
        }
}

// ---------------------------------------------------------------------------
// Pass C: out0 = sparse_conv(h0, W01, b01);  t = relu(sparse_conv(h1, W11, b11));
//         out1 = t @ W12 + b12;  out = [out0 | out1] + x  (fp32)
// Same coalesced-gather + bpermute scheme; one gather feeds both convs.
// ---------------------------------------------------------------------------
__global__ __launch_bounds__(256, 2) void passC_kernel(
    const unsigned short* __restrict__ hb, const int* __restrict__ nbr,
    const float* __restrict__ x,
    const unsigned short* __restrict__ wpC, const unsigned short* __restrict__ wp12,
    const float* __restrict__ b01, const float* __restrict__ b11,
    const float* __restrict__ b12, float* __restrict__ out, int N) {
    __shared__ __align__(16) unsigned short bbuf[2][8192];
    __shared__ int lds_idx[128 * 27];
    int tid = threadIdx.x;
    int lane = tid & 63;
    int wv   = tid >> 6;
    int q = lane >> 4, n16 = lane & 15;
    int rowq = lane >> 2, chunk = lane & 3;
    int sel = (n16 * 4 + q) * 4;
    int rowbase = blockIdx.x * 128 + wv * 32;

    {
        long long gbase = (long long)blockIdx.x * 128 * 27;
        long long lim = (long long)N * 27 - 1;
        for (int i = tid; i < 3456; i += 256) {
            long long gi = gbase + i; if (gi > lim) gi = lim;
            lds_idx[i] = nbr[gi];
        }
    }
    int4 br[4];
#pragma unroll
    for (int j = 0; j < 4; ++j) br[j] = *(const int4*)(wpC + j * 2048 + tid * 8);
#pragma unroll
    for (int j = 0; j < 4; ++j) *(int4*)(&bbuf[0][j * 2048 + tid * 8]) = br[j];
    __syncthreads();

    f32x4 accO0[2][4];
    f32x4 accT[2][4];
#pragma unroll
    for (int rs = 0; rs < 2; ++rs)
#pragma unroll
        for (int t = 0; t < 4; ++t) { accO0[rs][t] = (f32x4)0.f; accT[rs][t] = (f32x4)0.f; }

    int idxb0 = (wv * 32 + rowq) * 27;
    int idxb1 = (wv * 32 + 16 + rowq) * 27;

    int ia = lds_idx[idxb0], ib = lds_idx[idxb1];
    bf16x8 DA0[2], DC0[2], DA1[2], DC1[2];   // raw gathered (coalesced layout)
    {
        const unsigned short* p0 = hb + (size_t)ia * 128 + chunk * 8;
        const unsigned short* p1 = hb + (size_t)ib * 128 + chunk * 8;
#pragma unroll
        for (int s2 = 0; s2 < 2; ++s2) {
            DA0[s2] = *(const bf16x8*)(p0 + s2 * 32);
            DC0[s2] = *(const bf16x8*)(p0 + 64 + s2 * 32);
            DA1[s2] = *(const bf16x8*)(p1 + s2 * 32);
            DC1[s2] = *(const bf16x8*)(p1 + 64 + s2 * 32);
        }
    }

    for (int k = 0; k < 27; ++k) {
        int buf = k & 1;
        if (k < 26) {
            const unsigned short* src = wpC + (size_t)(k + 1) * 8192;
#pragma unroll
            for (int j = 0; j < 4; ++j) br[j] = *(const int4*)(src + j * 2048 + tid * 8);
        }
        bf16x8 DA0n[2], DC0n[2], DA1n[2], DC1n[2];
        if (k < 26) {
            int ian = lds_idx[idxb0 + k + 1];
            int ibn = lds_idx[idxb1 + k + 1];
            const unsigned short* p0 = hb + (size_t)ian * 128 + chunk * 8;
            const unsigned short* p1 = hb + (size_t)ibn * 128 + chunk * 8;
#pragma unroll
            for (int s2 = 0; s2 < 2; ++s2) {
                DA0n[s2] = *(const bf16x8*)(p0 + s2 * 32);
                DC0n[s2] = *(const bf16x8*)(p0 + 64 + s2 * 32);
                DA1n[s2] = *(const bf16x8*)(p1 + s2 * 32);
                DC1n[s2] = *(const bf16x8*)(p1 + 64 + s2 * 32);
            }
        }
        const unsigned short* lb = &bbuf[buf][0];
#pragma unroll
        for (int s2 = 0; s2 < 2; ++s2) {
            bf16x8 A0 = perm_frag(sel, DA0[s2]);
            bf16x8 A1 = perm_frag(sel, DA1[s2]);
#pragma unroll
            for (int t = 0; t < 4; ++t) {
                bf16x8 B = *(const bf16x8*)(lb + (s2 * 4 + t) * 512 + lane * 8);
                accO0[0][t] = MFMA(A0, B, accO0[0][t]);
                accO0[1][t] = MFMA(A1, B, accO0[1][t]);
            }
            bf16x8 C0 = perm_frag(sel, DC0[s2]);
            bf16x8 C1 = perm_frag(sel, DC1[s2]);
#pragma unroll
            for (int t = 0; t < 4; ++t) {
                bf16x8 B2 = *(const bf16x8*)(lb + 4096 + (s2 * 4 + t) * 512 + lane * 8);
                accT[0][t] = MFMA(C0, B2, accT[0][t]);
                accT[1][t] = MFMA(C1, B2, accT[1][t]);
            }
        }
        if (k < 26) {
#pragma unroll
            for (int j = 0; j < 4; ++j)
                *(int4*)(&bbuf[buf ^ 1][j * 2048 + tid * 8]) = br[j];
#pragma unroll
            for (int s2 = 0; s2 < 2; ++s2) {
                DA0[s2] = DA0n[s2]; DC0[s2] = DC0n[s2];
                DA1[s2] = DA1n[s2]; DC1[s2] = DC1n[s2];
            }
        }
        __syncthreads();   // final barrier also guards scratch reuse below
    }

    // epilogue 1: out0 (+bias +residual), t -> relu -> bf16 -> LDS scratch
    unsigned short* scratch = &bbuf[0][0];            // reuse B buffers
    unsigned short* myl = scratch + wv * 2304;        // 32 rows x 72 per wave
#pragma unroll
    for (int rs = 0; rs < 2; ++rs)
#pragma unroll
        for (int t = 0; t < 4; ++t) {
            int col = t * 16 + n16;
            float bo = b01[col], bt = b11[col];
#pragma unroll
            for (int r = 0; r < 4; ++r) {
                int row = rowbase + rs * 16 + q * 4 + r;
                if (row < N) {
                    float xv = __builtin_nontemporal_load(x + (size_t)row * 128 + col);
                    __builtin_nontemporal_store(accO0[rs][t][r] + bo + xv,
                                                out + (size_t)row * 128 + col);
                }
                float tv = fmaxf(accT[rs][t][r] + bt, 0.f);
                myl[(rs * 16 + q * 4 + r) * 72 + col] = f2b(tv);
            }
        }
    // per-wave private region: within-wave lgkmcnt ordering suffices (no barrier)

    // mini-GEMM: out1 = relu(t) @ W12
    f32x4 accO1[2][4];
#pragma unroll
    for (int rs = 0; rs < 2; ++rs)
#pragma unroll
        for (int t = 0; t < 4; ++t) accO1[rs][t] = (f32x4)0.f;
#pragma unroll
    for (int s2 = 0; s2 < 2; ++s2) {
        bf16x8 A0 = *(const bf16x8*)(myl + n16 * 72 + s2 * 32 + q * 8);
        bf16x8 A1 = *(const bf16x8*)(myl + (16 + n16) * 72 + s2 * 32 + q * 8);
#pragma unroll
        for (int t = 0; t < 4; ++t) {
            bf16x8 B = *(const bf16x8*)(wp12 + s2 * 2048 + t * 512 + lane * 8);
            accO1[0][t] = MFMA(A0, B, accO1[0][t]);
            accO1[1][t] = MFMA(A1, B, accO1[1][t]);
        }
    }
#pragma unroll
    for (int rs = 0; rs < 2; ++rs)
#pragma unroll
        for (int t = 0; t < 4; ++t) {
            int col = t * 16 + n16;
            float bo = b12[col];
#pragma unroll
            for (int r = 0; r < 4; ++r) {
                int row = rowbase + rs * 16 + q * 4 + r;
                if (row < N) {
                    float xv = __builtin_nontemporal_load(x + (size_t)row * 128 + 64 + col);
                    __builtin_nontemporal_store(accO1[rs][t][r] + bo + xv,
                                                out + (size_t)row * 128 + 64 + col);
                }
            }
        }
}

// ---------------------------------------------------------------------------
extern "C" void kernel_launch(void* const* d_in, const int* in_sizes, int n_in,
                              void* d_out, int out_size, void* d_ws, size_t ws_size,
                              hipStream_t stream) {
    const float* x   = (const float*)d_in[0];
    const int*   nbr = (const int*)d_in[1];
    const float* W00 = (const float*)d_in[2];
    const float* b00 = (const float*)d_in[3];
    const float* W01 = (const float*)d_in[4];
    const float* b01 = (const float*)d_in[5];
    const float* W10 = (const float*)d_in[6];
    const float* b10 = (const float*)d_in[7];
    const float* W11 = (const float*)d_in[8];
    const float* b11 = (const float*)d_in[9];
    const float* W12 = (const float*)d_in[10];
    const float* b12 = (const float*)d_in[11];
    float* out = (float*)d_out;
    int N = in_sizes[0] / 128;   // 100000

    // workspace carve-up
    char* ws = (char*)d_ws;
    size_t cur = 0;
    unsigned short* xb  = (unsigned short*)(ws + cur); cur += (size_t)(N + 1) * 128 * 2;
    unsigned short* hb  = (unsigned short*)(ws + cur); cur += (size_t)(N + 1) * 128 * 2;
    unsigned short* wp00 = (unsigned short*)(ws + cur); cur += 27648 * 8 * 2;
    unsigned short* wpC  = (unsigned short*)(ws + cur); cur += (size_t)27 * 8192 * 2;
    unsigned short* wp10 = (unsigned short*)(ws + cur); cur += 8192 * 2;
    unsigned short* wp12 = (unsigned short*)(ws + cur); cur += 4096 * 2;

    long long cvt_groups = ((long long)N * 128 + 128) / 4;
    int cvt_blocks = (int)((cvt_groups + 255) / 256);
    convert_kernel<<<cvt_blocks, 256, 0, stream>>>(x, xb, hb, N);
    pack_kernel<<<222, 256, 0, stream>>>(W00, W01, W10, W11, W12,
                                         wp00, wpC, wp10, wp12);
    int blocks = (N + 127) / 128;   // 782 blocks, 128 rows each
    passB_kernel<<<blocks, 256, 0, stream>>>(xb, nbr, wp00, wp10, b00, b10, hb, N);
    passC_kernel<<<blocks, 256, 0, stream>>>(hb, nbr, x, wpC, wp12,
                                             b01, b11, b12, out, N);
}

// Round 5
// 412.043 us; speedup vs baseline: 1.2936x; 1.0055x over previous
//
#include <hip/hip_runtime.h>
#include <hip/hip_bf16.h>
#include <stdint.h>

// MFMA fragment types (gfx950: mfma_f32_16x16x32_bf16 takes <8 x bf16>)
typedef __bf16 bf16x8 __attribute__((ext_vector_type(8)));
typedef float  f32x4  __attribute__((ext_vector_type(4)));

#define MFMA(A, B, C) __builtin_amdgcn_mfma_f32_16x16x32_bf16((A), (B), (C), 0, 0, 0)

// Raw workgroup barrier: waits LDS ops only, leaves global loads in flight
// (the compiler's __syncthreads() emits s_waitcnt vmcnt(0) which drains our
// gather prefetch every k-iteration — this is the structural stall).
#define LDS_BARRIER() asm volatile("s_waitcnt lgkmcnt(0)\n\ts_barrier" ::: "memory")

// fp32 -> bf16 round-to-nearest-even
static __device__ __forceinline__ unsigned short f2b(float f) {
    union { float f; unsigned int u; } v; v.f = f;
    return (unsigned short)((v.u + 0x7FFFu + ((v.u >> 16) & 1u)) >> 16);
}

// Redistribute a coalesced-gathered 16B fragment to MFMA A-layout.
// Gather layout: lane l holds row (l>>2), 16B chunk (l&3) of a 64B k-block.
// MFMA wants lane j = m + 16q to hold row m, chunk q -> pull from lane 4m+q.
static __device__ __forceinline__ bf16x8 perm_frag(int sel, bf16x8 D) {
    union { bf16x8 v; int d[4]; } u, r;
    u.v = D;
#pragma unroll
    for (int w = 0; w < 4; ++w) r.d[w] = __builtin_amdgcn_ds_bpermute(sel, u.d[w]);
    return r.v;
}

// ---------------------------------------------------------------------------
// Kernel 1: x fp32 -> bf16 [N+1][128]; zero pad row N of x_bf16 and h_comb.
// ---------------------------------------------------------------------------
__global__ __launch_bounds__(256) void convert_kernel(
    const float* __restrict__ x, unsigned short* __restrict__ xb,
    unsigned short* __restrict__ hb, int N) {
    long long i = (long long)blockIdx.x * blockDim.x + threadIdx.x; // 4 elems each
    long long base = i * 4;
    long long nx = (long long)N * 128;
    long long total = nx + 128;
    if (base >= total) return;
    if (base < nx) {
        float4 v = *(const float4*)(x + base);
        ushort4 o;
        o.x = f2b(v.x); o.y = f2b(v.y); o.z = f2b(v.z); o.w = f2b(v.w);
        *(ushort4*)(xb + base) = o;
    } else {
        ushort4 z = make_ushort4(0, 0, 0, 0);
        *(ushort4*)(xb + base) = z;   // pad row (index == N -> zeros)
        *(ushort4*)(hb + base) = z;
    }
}

// ---------------------------------------------------------------------------
// Kernel 2: pack weights into MFMA B-fragment order.
// wp00: per-k contiguous 16KB slices (k*8192 + (s2*4+t)*512 + lane*8).
// wpC : conv01 and conv11 k-slices interleaved: k*8192 + [0|4096] + ...
// ---------------------------------------------------------------------------
__global__ __launch_bounds__(256) void pack_kernel(
    const float* __restrict__ W00, const float* __restrict__ W01,
    const float* __restrict__ W10, const float* __restrict__ W11,
    const float* __restrict__ W12,
    unsigned short* __restrict__ wp00, unsigned short* __restrict__ wpC,
    unsigned short* __restrict__ wp10, unsigned short* __restrict__ wp12) {
    int g = blockIdx.x * blockDim.x + threadIdx.x;
    const float* W; int cinSteps; int which;
    if (g < 27648)      { W = W00; cinSteps = 4; which = 0; }
    else if (g < 41472) { g -= 27648; W = W01; cinSteps = 2; which = 1; }
    else if (g < 55296) { g -= 41472; W = W11; cinSteps = 2; which = 2; }
    else if (g < 56320) { g -= 55296; W = W10; cinSteps = 4; which = 3; }
    else if (g < 56832) { g -= 56320; W = W12; cinSteps = 2; which = 4; }
    else return;
    int lane = g & 63;
    int st   = g >> 6;
    int t    = st & 3;
    int s    = st >> 2;
    int q = lane >> 4, n16 = lane & 15;
    int k    = s / cinSteps;
    int cinb = (s % cinSteps) * 32;
    int Cin  = cinSteps * 32;
    int cout = t * 16 + n16;
    unsigned short o[8];
#pragma unroll
    for (int j = 0; j < 8; ++j) {
        float v = W[(size_t)(k * Cin + cinb + q * 8 + j) * 64 + cout];
        o[j] = f2b(v);
    }
    unsigned short* dst;
    if (which == 0)      dst = wp00 + (size_t)g * 8;
    else if (which == 1) dst = wpC + (size_t)k * 8192 +
                               ((size_t)(((s & 1) * 4 + t) * 64 + lane)) * 8;
    else if (which == 2) dst = wpC + (size_t)k * 8192 + 4096 +
                               ((size_t)(((s & 1) * 4 + t) * 64 + lane)) * 8;
    else if (which == 3) dst = wp10 + (size_t)g * 8;
    else                 dst = wp12 + (size_t)g * 8;
    *(ushort4*)(dst)     = make_ushort4(o[0], o[1], o[2], o[3]);
    *(ushort4*)(dst + 4) = make_ushort4(o[4], o[5], o[6], o[7]);
}

// ---------------------------------------------------------------------------
// Pass B: h0 = relu(sparse_conv(x, W00, b00)); h1 = relu(x @ W10 + b10)
// Persistent blocks steal 128-row strips via atomic counter.  32 rows/wave.
// B staged in LDS (double-buffered, raw LDS-only barrier per k so gather
// prefetches stay in flight across the barrier).  Coalesced gathers +
// ds_bpermute redistribution to MFMA A-layout.
// ---------------------------------------------------------------------------
__global__ __launch_bounds__(256, 2) void passB_kernel(
    const unsigned short* __restrict__ xb, const int* __restrict__ nbr,
    const unsigned short* __restrict__ wp00, const unsigned short* __restrict__ wp10,
    const float* __restrict__ b00, const float* __restrict__ b10,
    unsigned short* __restrict__ hb, int N, int* __restrict__ ctr, int nstrips) {
    __shared__ __align__(16) unsigned short bbuf[2][8192];
    __shared__ int lds_idx[128 * 27];
    __shared__ int sstrip;
    int tid = threadIdx.x;
    int lane = tid & 63;
    int wv   = tid >> 6;
    int q = lane >> 4, n16 = lane & 15;
    int rowq = lane >> 2, chunk = lane & 3;
    int sel = (n16 * 4 + q) * 4;            // bpermute byte index

    for (;;) {
        if (tid == 0) sstrip = atomicAdd(ctr, 1);
        __syncthreads();
        int strip = sstrip;
        if (strip >= nstrips) break;
        int rowbase = strip * 128 + wv * 32;

        // stage B(0) (issue first) and the strip's nbr slice
        int4 br[4];
#pragma unroll
        for (int j = 0; j < 4; ++j) br[j] = *(const int4*)(wp00 + j * 2048 + tid * 8);
        {
            long long gbase = (long long)strip * 128 * 27;
            long long lim = (long long)N * 27 - 1;
            for (int i = tid; i < 3456; i += 256) {
                long long gi = gbase + i; if (gi > lim) gi = lim;
                lds_idx[i] = nbr[gi];
            }
        }
#pragma unroll
        for (int j = 0; j < 4; ++j) *(int4*)(&bbuf[0][j * 2048 + tid * 8]) = br[j];
        __syncthreads();

        f32x4 acc0[2][4];   // conv0_0 accum [rowset][t]
        f32x4 acc1[2][4];   // conv1_0 (1x1) accum
#pragma unroll
        for (int rs = 0; rs < 2; ++rs)
#pragma unroll
            for (int t = 0; t < 4; ++t) { acc0[rs][t] = (f32x4)0.f; acc1[rs][t] = (f32x4)0.f; }

        int idxb0 = (wv * 32 + rowq) * 27;          // rowset 0, this lane's row
        int idxb1 = (wv * 32 + 16 + rowq) * 27;     // rowset 1
        int own0 = min(rowbase + rowq, N - 1);      // own rows (coalesced mapping)
        int own1 = min(rowbase + 16 + rowq, N - 1);

        // raw gather D(0)
        int ia = lds_idx[idxb0], ib = lds_idx[idxb1];
        bf16x8 D0[4], D1[4];
        {
            const unsigned short* p0 = xb + (size_t)ia * 128 + chunk * 8;
            const unsigned short* p1 = xb + (size_t)ib * 128 + chunk * 8;
#pragma unroll
            for (int s2 = 0; s2 < 4; ++s2) {
                D0[s2] = *(const bf16x8*)(p0 + s2 * 32);
                D1[s2] = *(const bf16x8*)(p1 + s2 * 32);
            }
        }

        for (int k = 0; k < 27; ++k) {
            int buf = k & 1;
            if (k < 26) {   // B(k+1) global -> regs (issued BEFORE gathers)
                const unsigned short* src = wp00 + (size_t)(k + 1) * 8192;
#pragma unroll
                for (int j = 0; j < 4; ++j) br[j] = *(const int4*)(src + j * 2048 + tid * 8);
            }
            // next gather: idx(k+1) from LDS; past end -> own row (feeds 1x1)
            int ian = (k + 1 < 27) ? lds_idx[idxb0 + k + 1] : own0;
            int ibn = (k + 1 < 27) ? lds_idx[idxb1 + k + 1] : own1;
            bf16x8 D0n[4], D1n[4];
            {
                const unsigned short* p0 = xb + (size_t)ian * 128 + chunk * 8;
                const unsigned short* p1 = xb + (size_t)ibn * 128 + chunk * 8;
#pragma unroll
                for (int s2 = 0; s2 < 4; ++s2) {
                    D0n[s2] = *(const bf16x8*)(p0 + s2 * 32);
                    D1n[s2] = *(const bf16x8*)(p1 + s2 * 32);
                }
            }
            // redistribute D(k) to MFMA layout, then MFMA with LDS B(k)
            const unsigned short* lb = &bbuf[buf][0];
#pragma unroll
            for (int s2 = 0; s2 < 4; ++s2) {
                bf16x8 A0 = perm_frag(sel, D0[s2]);
                bf16x8 A1 = perm_frag(sel, D1[s2]);
#pragma unroll
                for (int t = 0; t < 4; ++t) {
                    bf16x8 B = *(const bf16x8*)(lb + (s2 * 4 + t) * 512 + lane * 8);
                    acc0[0][t] = MFMA(A0, B, acc0[0][t]);
                    acc0[1][t] = MFMA(A1, B, acc0[1][t]);
                }
            }
            if (k < 26) {   // auto vmcnt here only drains B loads (older than gathers)
#pragma unroll
                for (int j = 0; j < 4; ++j)
                    *(int4*)(&bbuf[buf ^ 1][j * 2048 + tid * 8]) = br[j];
            }
#pragma unroll
            for (int s2 = 0; s2 < 4; ++s2) { D0[s2] = D0n[s2]; D1[s2] = D1n[s2]; }
            LDS_BARRIER();   // LDS-only drain: gathers stay in flight
        }

        // fused 1x1 conv: D now holds the wave's own rows
#pragma unroll
        for (int s2 = 0; s2 < 4; ++s2) {
            bf16x8 A0 = perm_frag(sel, D0[s2]);
            bf16x8 A1 = perm_frag(sel, D1[s2]);
#pragma unroll
            for (int t = 0; t < 4; ++t) {
                bf16x8 B = *(const bf16x8*)(wp10 + s2 * 2048 + t * 512 + lane * 8);
                acc1[0][t] = MFMA(A0, B, acc1[0][t]);
                acc1[1][t] = MFMA(A1, B, acc1[1][t]);
            }
        }

        // epilogue: bias, relu, -> bf16, store h_comb.  C-layout: col=lane&15
#pragma unroll
        for (int rs = 0; rs < 2; ++rs)
#pragma unroll
            for (int t = 0; t < 4; ++t) {
                int col = t * 16 + n16;
                float bb0 = b00[col], bb1 = b10[col];
#pragma unroll
                for (int r = 0; r < 4; ++r) {
                    int row = rowbase + rs * 16 + q * 4 + r;
                    if (row < N) {
                        hb[(size_t)row * 128 + col]      = f2b(fmaxf(acc0[rs][t][r] + bb0, 0.f));
                        hb[(size_t)row * 128 + 64 + col] = f2b(fmaxf(acc1[rs][t][r] + bb1, 0.f));
                    }
                }
            }
        __syncthreads();   // protect lds_idx/bbuf/sstrip reuse for next strip
    }
}

// ---------------------------------------------------------------------------
// Pass C: out0 = sparse_conv(h0, W01, b01);  t = relu(sparse_conv(h1, W11, b11));
//         out1 = t @ W12 + b12;  out = [out0 | out1] + x  (fp32)
// Same persistent-strip + raw-barrier structure; one gather feeds both convs.
// ---------------------------------------------------------------------------
__global__ __launch_bounds__(256, 2) void passC_kernel(
    const unsigned short* __restrict__ hb, const int* __restrict__ nbr,
    const float* __restrict__ x,
    const unsigned short* __restrict__ wpC, const unsigned short* __restrict__ wp12,
    const float* __restrict__ b01, const float* __restrict__ b11,
    const float* __restrict__ b12, float* __restrict__ out, int N,
    int* __restrict__ ctr, int nstrips) {
    __shared__ __align__(16) unsigned short bbuf[2][8192];
    __shared__ int lds_idx[128 * 27];
    __shared__ int sstrip;
    int tid = threadIdx.x;
    int lane = tid & 63;
    int wv   = tid >> 6;
    int q = lane >> 4, n16 = lane & 15;
    int rowq = lane >> 2, chunk = lane & 3;
    int sel = (n16 * 4 + q) * 4;

    for (;;) {
        if (tid == 0) sstrip = atomicAdd(ctr, 1);
        __syncthreads();
        int strip = sstrip;
        if (strip >= nstrips) break;
        int rowbase = strip * 128 + wv * 32;

        int4 br[4];
#pragma unroll
        for (int j = 0; j < 4; ++j) br[j] = *(const int4*)(wpC + j * 2048 + tid * 8);
        {
            long long gbase = (long long)strip * 128 * 27;
            long long lim = (long long)N * 27 - 1;
            for (int i = tid; i < 3456; i += 256) {
                long long gi = gbase + i; if (gi > lim) gi = lim;
                lds_idx[i] = nbr[gi];
            }
        }
#pragma unroll
        for (int j = 0; j < 4; ++j) *(int4*)(&bbuf[0][j * 2048 + tid * 8]) = br[j];
        __syncthreads();

        f32x4 accO0[2][4];
        f32x4 accT[2][4];
#pragma unroll
        for (int rs = 0; rs < 2; ++rs)
#pragma unroll
            for (int t = 0; t < 4; ++t) { accO0[rs][t] = (f32x4)0.f; accT[rs][t] = (f32x4)0.f; }

        int idxb0 = (wv * 32 + rowq) * 27;
        int idxb1 = (wv * 32 + 16 + rowq) * 27;

        int ia = lds_idx[idxb0], ib = lds_idx[idxb1];
        bf16x8 DA0[2], DC0[2], DA1[2], DC1[2];   // raw gathered (coalesced)
        {
            const unsigned short* p0 = hb + (size_t)ia * 128 + chunk * 8;
            const unsigned short* p1 = hb + (size_t)ib * 128 + chunk * 8;
#pragma unroll
            for (int s2 = 0; s2 < 2; ++s2) {
                DA0[s2] = *(const bf16x8*)(p0 + s2 * 32);
                DC0[s2] = *(const bf16x8*)(p0 + 64 + s2 * 32);
                DA1[s2] = *(const bf16x8*)(p1 + s2 * 32);
                DC1[s2] = *(const bf16x8*)(p1 + 64 + s2 * 32);
            }
        }

        for (int k = 0; k < 27; ++k) {
            int buf = k & 1;
            if (k < 26) {
                const unsigned short* src = wpC + (size_t)(k + 1) * 8192;
#pragma unroll
                for (int j = 0; j < 4; ++j) br[j] = *(const int4*)(src + j * 2048 + tid * 8);
            }
            bf16x8 DA0n[2], DC0n[2], DA1n[2], DC1n[2];
            if (k < 26) {
                int ian = lds_idx[idxb0 + k + 1];
                int ibn = lds_idx[idxb1 + k + 1];
                const unsigned short* p0 = hb + (size_t)ian * 128 + chunk * 8;
                const unsigned short* p1 = hb + (size_t)ibn * 128 + chunk * 8;
#pragma unroll
                for (int s2 = 0; s2 < 2; ++s2) {
                    DA0n[s2] = *(const bf16x8*)(p0 + s2 * 32);
                    DC0n[s2] = *(const bf16x8*)(p0 + 64 + s2 * 32);
                    DA1n[s2] = *(const bf16x8*)(p1 + s2 * 32);
                    DC1n[s2] = *(const bf16x8*)(p1 + 64 + s2 * 32);
                }
            }
            const unsigned short* lb = &bbuf[buf][0];
#pragma unroll
            for (int s2 = 0; s2 < 2; ++s2) {
                bf16x8 A0 = perm_frag(sel, DA0[s2]);
                bf16x8 A1 = perm_frag(sel, DA1[s2]);
#pragma unroll
                for (int t = 0; t < 4; ++t) {
                    bf16x8 B = *(const bf16x8*)(lb + (s2 * 4 + t) * 512 + lane * 8);
                    accO0[0][t] = MFMA(A0, B, accO0[0][t]);
                    accO0[1][t] = MFMA(A1, B, accO0[1][t]);
                }
                bf16x8 C0 = perm_frag(sel, DC0[s2]);
                bf16x8 C1 = perm_frag(sel, DC1[s2]);
#pragma unroll
                for (int t = 0; t < 4; ++t) {
                    bf16x8 B2 = *(const bf16x8*)(lb + 4096 + (s2 * 4 + t) * 512 + lane * 8);
                    accT[0][t] = MFMA(C0, B2, accT[0][t]);
                    accT[1][t] = MFMA(C1, B2, accT[1][t]);
                }
            }
            if (k < 26) {
#pragma unroll
                for (int j = 0; j < 4; ++j)
                    *(int4*)(&bbuf[buf ^ 1][j * 2048 + tid * 8]) = br[j];
#pragma unroll
                for (int s2 = 0; s2 < 2; ++s2) {
                    DA0[s2] = DA0n[s2]; DC0[s2] = DC0n[s2];
                    DA1[s2] = DA1n[s2]; DC1[s2] = DC1n[s2];
                }
            }
            LDS_BARRIER();   // also guards bbuf scratch reuse below
        }

        // epilogue 1: out0 (+bias +residual), t -> relu -> bf16 -> LDS scratch
        unsigned short* scratch = &bbuf[0][0];            // reuse B buffers
        unsigned short* myl = scratch + wv * 2304;        // 32 rows x 72/wave
#pragma unroll
        for (int rs = 0; rs < 2; ++rs)
#pragma unroll
            for (int t = 0; t < 4; ++t) {
                int col = t * 16 + n16;
                float bo = b01[col], bt = b11[col];
#pragma unroll
                for (int r = 0; r < 4; ++r) {
                    int row = rowbase + rs * 16 + q * 4 + r;
                    if (row < N) {
                        float xv = __builtin_nontemporal_load(x + (size_t)row * 128 + col);
                        __builtin_nontemporal_store(accO0[rs][t][r] + bo + xv,
                                                    out + (size_t)row * 128 + col);
                    }
                    float tv = fmaxf(accT[rs][t][r] + bt, 0.f);
                    myl[(rs * 16 + q * 4 + r) * 72 + col] = f2b(tv);
                }
            }
        // per-wave private region: within-wave lgkm ordering suffices

        // mini-GEMM: out1 = relu(t) @ W12
        f32x4 accO1[2][4];
#pragma unroll
        for (int rs = 0; rs < 2; ++rs)
#pragma unroll
            for (int t = 0; t < 4; ++t) accO1[rs][t] = (f32x4)0.f;
#pragma unroll
        for (int s2 = 0; s2 < 2; ++s2) {
            bf16x8 A0 = *(const bf16x8*)(myl + n16 * 72 + s2 * 32 + q * 8);
            bf16x8 A1 = *(const bf16x8*)(myl + (16 + n16) * 72 + s2 * 32 + q * 8);
#pragma unroll
            for (int t = 0; t < 4; ++t) {
                bf16x8 B = *(const bf16x8*)(wp12 + s2 * 2048 + t * 512 + lane * 8);
                accO1[0][t] = MFMA(A0, B, accO1[0][t]);
                accO1[1][t] = MFMA(A1, B, accO1[1][t]);
            }
        }
#pragma unroll
        for (int rs = 0; rs < 2; ++rs)
#pragma unroll
            for (int t = 0; t < 4; ++t) {
                int col = t * 16 + n16;
                float bo = b12[col];
#pragma unroll
                for (int r = 0; r < 4; ++r) {
                    int row = rowbase + rs * 16 + q * 4 + r;
                    if (row < N) {
                        float xv = __builtin_nontemporal_load(x + (size_t)row * 128 + 64 + col);
                        __builtin_nontemporal_store(accO1[rs][t][r] + bo + xv,
                                                    out + (size_t)row * 128 + 64 + col);
                    }
                }
            }
        __syncthreads();   // protect lds_idx/bbuf/sstrip reuse for next strip
    }
}

// ---------------------------------------------------------------------------
extern "C" void kernel_launch(void* const* d_in, const int* in_sizes, int n_in,
                              void* d_out, int out_size, void* d_ws, size_t ws_size,
                              hipStream_t stream) {
    const float* x   = (const float*)d_in[0];
    const int*   nbr = (const int*)d_in[1];
    const float* W00 = (const float*)d_in[2];
    const float* b00 = (const float*)d_in[3];
    const float* W01 = (const float*)d_in[4];
    const float* b01 = (const float*)d_in[5];
    const float* W10 = (const float*)d_in[6];
    const float* b10 = (const float*)d_in[7];
    const float* W11 = (const float*)d_in[8];
    const float* b11 = (const float*)d_in[9];
    const float* W12 = (const float*)d_in[10];
    const float* b12 = (const float*)d_in[11];
    float* out = (float*)d_out;
    int N = in_sizes[0] / 128;   // 100000

    // workspace carve-up
    char* ws = (char*)d_ws;
    size_t cur = 0;
    unsigned short* xb  = (unsigned short*)(ws + cur); cur += (size_t)(N + 1) * 128 * 2;
    unsigned short* hb  = (unsigned short*)(ws + cur); cur += (size_t)(N + 1) * 128 * 2;
    unsigned short* wp00 = (unsigned short*)(ws + cur); cur += 27648 * 8 * 2;
    unsigned short* wpC  = (unsigned short*)(ws + cur); cur += (size_t)27 * 8192 * 2;
    unsigned short* wp10 = (unsigned short*)(ws + cur); cur += 8192 * 2;
    unsigned short* wp12 = (unsigned short*)(ws + cur); cur += 4096 * 2;
    cur = (cur + 255) & ~(size_t)255;
    int* ctrs = (int*)(ws + cur); cur += 256;   // [0]=passB, [1]=passC

    hipMemsetAsync(ctrs, 0, 8, stream);
    long long cvt_groups = ((long long)N * 128 + 128) / 4;
    int cvt_blocks = (int)((cvt_groups + 255) / 256);
    convert_kernel<<<cvt_blocks, 256, 0, stream>>>(x, xb, hb, N);
    pack_kernel<<<222, 256, 0, stream>>>(W00, W01, W10, W11, W12,
                                         wp00, wpC, wp10, wp12);
    int nstrips = (N + 127) / 128;   // 782 strips of 128 rows
    passB_kernel<<<768, 256, 0, stream>>>(xb, nbr, wp00, wp10, b00, b10, hb, N,
                                          ctrs + 0, nstrips);
    passC_kernel<<<768, 256, 0, stream>>>(hb, nbr, x, wpC, wp12,
                                          b01, b11, b12, out, N,
                                          ctrs + 1, nstrips);
}